// Round 9
// baseline (738.641 us; speedup 1.0000x reference)
//
#include <hip/hip_runtime.h>

#define S    8192
#define Dm   4096
#define E    64
#define CAP  128
#define CCH  32          // split-K chunks
#define KC   (Dm/CCH)    // 128 k per chunk
#define KSUB 16          // k sub-tile staged in LDS
#define XSTR 260         // xs row stride: 2-way store conflicts only (free)
#define WSTR 68          // ws row stride: 2-way store conflicts only (free)

#define CW_OFF 1
#define DM_OFF (1 + (size_t)S*E*CAP)
#define EC_OFF (1 + 2*(size_t)S*E*CAP)
// out_size = 1 + 2*S*E*CAP + 64 = 134217793 elements
#define OUT_F4   33554432u   // float4s covering [0, 134217728)
#define BLK_F4   32768u      // float4s zero-filled per k1 block (1024 blocks)

// ---------------- K1: register-tiled partial GEMM + fused out zero-fill -----
// block: 256 tokens x 64 experts x 128 k. thread: 8 tokens x 8 experts (acc[64]).
// (R6 structure — best of 5 tilings.) Each block also zeroes 512 KB of out,
// 16 float4/thread per su, overlapped with compute via 4-blocks/CU stagger.
__global__ __launch_bounds__(256, 4)
void k1_partial(const float* __restrict__ x, const float* __restrict__ wg,
                float* __restrict__ part, float* __restrict__ out) {
    __shared__ float xs[KSUB][XSTR];   // [k][token]
    __shared__ float wsh[KSUB][WSTR];  // [k][e]
    const int tb  = blockIdx.x >> 5;   // 0..31 token block (256 tokens)
    const int c   = blockIdx.x & 31;   // 0..31 k chunk (128 k)
    const int tid = threadIdx.x;
    const int tt  = tid & 31;          // token group (8 tokens)
    const int ee  = tid >> 5;          // expert group (8 experts)
    const int k0  = c * KC;

    float acc[64];
    #pragma unroll
    for (int i = 0; i < 64; i++) acc[i] = 0.f;

    const int xr = tid >> 2;           // 0..63 token row base
    const int xc = tid & 3;            // float4 col within 16 k
    const int we = tid >> 2;           // 0..63 expert (W staging)
    const int wk = (tid & 3) * 4;      // k quad (W staging)

    float4* outv = (float4*)out;
    const size_t fbase = (size_t)blockIdx.x * BLK_F4 + tid;
    const float4 z4 = make_float4(0.f, 0.f, 0.f, 0.f);

    for (int su = 0; su < KC / KSUB; su++) {
        const int ks0 = k0 + su * KSUB;
        // stage x: 256 tokens x 16 k, transposed into xs[k][token]
        #pragma unroll
        for (int i = 0; i < 4; i++) {
            const int row = i * 64 + xr;
            const float4 v = *(const float4*)(x + (size_t)(tb*256 + row) * Dm + ks0 + xc*4);
            xs[xc*4+0][row] = v.x;
            xs[xc*4+1][row] = v.y;
            xs[xc*4+2][row] = v.z;
            xs[xc*4+3][row] = v.w;
        }
        // stage W: 64 e x 16 k from wg, transposed into ws[k][e]
        {
            const float4 v = *(const float4*)(wg + (size_t)we * Dm + ks0 + wk);
            wsh[wk+0][we] = v.x; wsh[wk+1][we] = v.y;
            wsh[wk+2][we] = v.z; wsh[wk+3][we] = v.w;
        }
        // fused zero-fill chunk: 16 float4/thread, drained by the barrier while
        // the CU's other 3 blocks compute
        #pragma unroll
        for (int i = 0; i < 16; i++)
            outv[fbase + (size_t)(su * 16 + i) * 256] = z4;
        __syncthreads();
        #pragma unroll 4
        for (int kk = 0; kk < KSUB; kk++) {
            const float4 a0 = *(const float4*)&xs[kk][tt*8];
            const float4 a1 = *(const float4*)&xs[kk][tt*8+4];
            const float4 w0 = *(const float4*)&wsh[kk][ee*8];
            const float4 w1 = *(const float4*)&wsh[kk][ee*8+4];
            const float av[8] = {a0.x,a0.y,a0.z,a0.w,a1.x,a1.y,a1.z,a1.w};
            const float wv[8] = {w0.x,w0.y,w0.z,w0.w,w1.x,w1.y,w1.z,w1.w};
            #pragma unroll
            for (int t = 0; t < 8; t++)
                #pragma unroll
                for (int e = 0; e < 8; e++)
                    acc[t*8+e] = fmaf(av[t], wv[e], acc[t*8+e]);
        }
        __syncthreads();
    }
    // tail of out: elements [134217728, 134217793)
    if (blockIdx.x == 0) {
        if (tid < 16) outv[OUT_F4 + tid] = z4;
        if (tid == 16) out[(size_t)OUT_F4 * 4 + 64] = 0.f;
    }
    // part[c][token][e]
    #pragma unroll
    for (int t = 0; t < 8; t++) {
        float* dst = part + ((size_t)c * S + tb*256 + tt*8 + t) * E + ee*8;
        *(float4*)(dst)     = make_float4(acc[t*8+0], acc[t*8+1], acc[t*8+2], acc[t*8+3]);
        *(float4*)(dst + 4) = make_float4(acc[t*8+4], acc[t*8+5], acc[t*8+6], acc[t*8+7]);
    }
}

// ---------------- K1b: reduce partials, softmax, argmax, me atomics ----------
__global__ __launch_bounds__(256, 1)
void k1b_softmax(const float* __restrict__ part, float* __restrict__ gate_val,
                 int* __restrict__ idx1, int* __restrict__ counts,
                 float* __restrict__ me_sum) {
    const int tid = threadIdx.x, wv = tid >> 6, ln = tid & 63;
    const int token = blockIdx.x * 4 + wv;
    float p = 0.f;
    #pragma unroll
    for (int c = 0; c < CCH; c++) p += part[((size_t)c * S + token) * E + ln];
    // argmax (max value, lowest index on ties) — matches jnp.argmax
    float v = p; int i = ln;
    #pragma unroll
    for (int off = 1; off < 64; off <<= 1) {
        float ov = __shfl_xor(v, off, 64);
        int   oi = __shfl_xor(i, off, 64);
        if (ov > v || (ov == v && oi < i)) { v = ov; i = oi; }
    }
    float g = __expf(p - v);
    float ssum = g;
    #pragma unroll
    for (int off = 1; off < 64; off <<= 1) ssum += __shfl_xor(ssum, off, 64);
    const float gate = g / ssum;
    __shared__ float gs[4][64];
    gs[wv][ln] = gate;
    __syncthreads();
    if (tid < 64)
        atomicAdd(&me_sum[tid], gs[0][tid] + gs[1][tid] + gs[2][tid] + gs[3][tid]);
    if (ln == 0) {
        gate_val[token] = 1.0f / ssum;
        idx1[token] = i;
        atomicAdd(&counts[i], 1);
    }
}

// ---------------- K2: per-expert capacity selection + scatter ----------------
__device__ __forceinline__ int block_reduce_sum(int v, int* tmp4, int tid) {
    #pragma unroll
    for (int off = 1; off < 64; off <<= 1) v += __shfl_xor(v, off, 64);
    __syncthreads();
    if ((tid & 63) == 0) tmp4[tid >> 6] = v;
    __syncthreads();
    return tmp4[0] + tmp4[1] + tmp4[2] + tmp4[3];
}

__device__ __forceinline__ int block_scan_incl(int val, int* a, int* b, int tid, int* total) {
    __syncthreads();
    a[tid] = val;
    __syncthreads();
    int* src = a; int* dst = b;
    #pragma unroll
    for (int off = 1; off < 256; off <<= 1) {
        int v = src[tid];
        if (tid >= off) v += src[tid - off];
        dst[tid] = v;
        __syncthreads();
        int* t = src; src = dst; dst = t;
    }
    *total = src[255];
    return src[tid];
}

__global__ __launch_bounds__(256, 1)
void k2_select(const int* __restrict__ idx1, const float* __restrict__ gate_val,
               const float* __restrict__ noise, const int* __restrict__ counts,
               const float* __restrict__ me_sum, float* __restrict__ out) {
    const int e = blockIdx.x;
    const int tid = threadIdx.x;
    __shared__ int idx_s[S];
    __shared__ unsigned short l_tok[S];
    __shared__ float l_ns[S];
    __shared__ int sa[256], sb[256];
    __shared__ int tmp4[4];

    for (int i = tid; i < S; i += 256) idx_s[i] = idx1[i];
    __syncthreads();

    int cnt = 0;
    #pragma unroll
    for (int j4 = 0; j4 < 8; j4++) {
        const int4 q = *(const int4*)&idx_s[tid * 32 + j4 * 4];
        cnt += (q.x == e) + (q.y == e) + (q.z == e) + (q.w == e);
    }
    int total_n;
    int incl = block_scan_incl(cnt, sa, sb, tid, &total_n);
    int pos = incl - cnt;
    const int n = total_n;
    #pragma unroll
    for (int j4 = 0; j4 < 8; j4++) {
        const int4 q = *(const int4*)&idx_s[tid * 32 + j4 * 4];
        const int qv[4] = {q.x, q.y, q.z, q.w};
        #pragma unroll
        for (int u = 0; u < 4; u++) {
            const int s = tid * 32 + j4 * 4 + u;
            if (qv[u] == e) {
                l_tok[pos] = (unsigned short)s;
                l_ns[pos]  = noise[(size_t)s * E + e];
                pos++;
            }
        }
    }
    __syncthreads();

    if (tid == 0) out[EC_OFF + e] = (float)n;   // exp_counts (pre-capacity)

    // 128th-largest noise via binary search on positive-float bit patterns
    unsigned int V = 0u;
    if (n > CAP) {
        unsigned int lo = 0u, hi = 0x3F800000u;
        while (hi - lo > 1u) {
            const unsigned int mid = (lo + hi) >> 1;
            int c = 0;
            for (int i2 = tid; i2 < n; i2 += 256)
                c += (__float_as_uint(l_ns[i2]) >= mid);
            const int cge = block_reduce_sum(c, tmp4, tid);
            if (cge >= CAP) lo = mid; else hi = mid;
        }
        V = lo;
    }

    const int m = (n + 255) >> 8;
    const int i_begin = min(n, tid * m);
    const int i_end   = min(n, i_begin + m);
    int gt_l = 0, eq_l = 0;
    for (int i2 = i_begin; i2 < i_end; i2++) {
        const unsigned int b = __float_as_uint(l_ns[i2]);
        gt_l += (b > V); eq_l += (b == V);
    }
    int tot_gt, tot_eq;
    const int incl_gt = block_scan_incl(gt_l, sa, sb, tid, &tot_gt);
    (void)incl_gt;
    const int incl_eq = block_scan_incl(eq_l, sa, sb, tid, &tot_eq);
    const int eq_excl = incl_eq - eq_l;
    const int take_eq = CAP - tot_gt;   // ties -> lowest token index (jax top_k stable)
    const int sel_l = gt_l + max(0, min(eq_l, take_eq - eq_excl));
    int tot_sel;
    const int incl_sel = block_scan_incl(sel_l, sa, sb, tid, &tot_sel);
    int slot = incl_sel - sel_l;
    int eq_seen = eq_excl;
    for (int i2 = i_begin; i2 < i_end; i2++) {
        const unsigned int b = __float_as_uint(l_ns[i2]);
        bool sel;
        if (b > V) sel = true;
        else if (b == V) { sel = (eq_seen < take_eq); eq_seen++; }
        else sel = false;
        if (sel) {
            const int tok = l_tok[i2];
            const float g = gate_val[tok];
            const size_t off = (size_t)tok * (E * CAP) + (size_t)e * CAP + slot;
            out[CW_OFF + off] = g;
            out[DM_OFF + off] = 1.0f;
            slot++;
        }
    }

    if (e == 0 && tid < 64) {
        float la = (me_sum[tid] / (float)S) * ((float)counts[tid] / (float)S);
        #pragma unroll
        for (int off = 1; off < 64; off <<= 1) la += __shfl_xor(la, off, 64);
        if (tid == 0) out[0] = la * (float)E;
    }
}

extern "C" void kernel_launch(void* const* d_in, const int* in_sizes, int n_in,
                              void* d_out, int out_size, void* d_ws, size_t ws_size,
                              hipStream_t stream) {
    const float* x     = (const float*)d_in[0];
    const float* wg    = (const float*)d_in[1];
    const float* noise = (const float*)d_in[2];
    float* out = (float*)d_out;
    float* ws  = (float*)d_ws;

    float* gate_val = ws;                   // 8192 f32
    int*   idx1     = (int*)(ws + 8192);    // 8192 i32
    int*   counts   = (int*)(ws + 16384);   // 64 i32
    float* me_sum   = ws + 16448;           // 64 f32
    float* part     = ws + 16512;           // 32*8192*64 f32 = 67 MB (L2/L3-resident)

    hipMemsetAsync(counts, 0, 128 * sizeof(int), stream);      // counts + me_sum
    k1_partial  <<<dim3(1024), dim3(256), 0, stream>>>(x, wg, part, out);
    k1b_softmax <<<dim3(S/4),  dim3(256), 0, stream>>>(part, gate_val, idx1, counts, me_sum);
    k2_select   <<<dim3(E),    dim3(256), 0, stream>>>(idx1, gate_val, noise, counts, me_sum, out);
}

// Round 10
// 712.741 us; speedup vs baseline: 1.0363x; 1.0363x over previous
//
#include <hip/hip_runtime.h>

#define S    8192
#define Dm   4096
#define E    64
#define CAP  128
#define CCH  32          // split-K chunks
#define KC   (Dm/CCH)    // 128 k per chunk
#define KSUB 16          // k sub-tile staged in LDS
#define XSTR 260         // xs row stride: 2-way store conflicts only (free)
#define WSTR 68          // ws row stride: 2-way store conflicts only (free)

#define CW_OFF 1
#define DM_OFF (1 + (size_t)S*E*CAP)
#define EC_OFF (1 + 2*(size_t)S*E*CAP)

// ---------------- K1: register-tiled partial GEMM (R6 + bank-spread a-reads)
// block: 256 tokens x 64 experts x 128 k. thread: 8 tokens x 8 experts (acc[64]).
// Token ownership split into two quads (tt*4, 128+tt*4): consecutive lanes read
// consecutive 16B -> all 32 banks active on a-reads (4cy vs 8cy).
__global__ __launch_bounds__(256, 4)
void k1_partial(const float* __restrict__ x, const float* __restrict__ wg,
                float* __restrict__ part) {
    __shared__ float xs[KSUB][XSTR];   // [k][token]
    __shared__ float wsh[KSUB][WSTR];  // [k][e]
    const int tb  = blockIdx.x >> 5;   // 0..31 token block (256 tokens)
    const int c   = blockIdx.x & 31;   // 0..31 k chunk (128 k)
    const int tid = threadIdx.x;
    const int tt  = tid & 31;          // token group
    const int ee  = tid >> 5;          // expert group (8 experts)
    const int k0  = c * KC;

    float acc[64];
    #pragma unroll
    for (int i = 0; i < 64; i++) acc[i] = 0.f;

    const int xr = tid >> 2;           // 0..63 token row base
    const int xc = tid & 3;            // float4 col within 16 k
    const int we = tid >> 2;           // 0..63 expert (W staging)
    const int wk = (tid & 3) * 4;      // k quad (W staging)

    for (int su = 0; su < KC / KSUB; su++) {
        const int ks0 = k0 + su * KSUB;
        // stage x: 256 tokens x 16 k, transposed into xs[k][token]
        #pragma unroll
        for (int i = 0; i < 4; i++) {
            const int row = i * 64 + xr;
            const float4 v = *(const float4*)(x + (size_t)(tb*256 + row) * Dm + ks0 + xc*4);
            xs[xc*4+0][row] = v.x;
            xs[xc*4+1][row] = v.y;
            xs[xc*4+2][row] = v.z;
            xs[xc*4+3][row] = v.w;
        }
        // stage W: 64 e x 16 k from wg, transposed into ws[k][e]
        {
            const float4 v = *(const float4*)(wg + (size_t)we * Dm + ks0 + wk);
            wsh[wk+0][we] = v.x; wsh[wk+1][we] = v.y;
            wsh[wk+2][we] = v.z; wsh[wk+3][we] = v.w;
        }
        __syncthreads();
        #pragma unroll 4
        for (int kk = 0; kk < KSUB; kk++) {
            const float4 a0 = *(const float4*)&xs[kk][tt*4];        // tokens tt*4..+3
            const float4 a1 = *(const float4*)&xs[kk][128 + tt*4];  // tokens 128+tt*4..+3
            const float4 w0 = *(const float4*)&wsh[kk][ee*8];
            const float4 w1 = *(const float4*)&wsh[kk][ee*8+4];
            const float av[8] = {a0.x,a0.y,a0.z,a0.w,a1.x,a1.y,a1.z,a1.w};
            const float wv[8] = {w0.x,w0.y,w0.z,w0.w,w1.x,w1.y,w1.z,w1.w};
            #pragma unroll
            for (int t = 0; t < 8; t++)
                #pragma unroll
                for (int e = 0; e < 8; e++)
                    acc[t*8+e] = fmaf(av[t], wv[e], acc[t*8+e]);
        }
        __syncthreads();
    }
    // part[c][token][e]; thread owns tokens tt*4+i and 128+tt*4+i
    #pragma unroll
    for (int t = 0; t < 8; t++) {
        const int token = (t < 4) ? (tt*4 + t) : (128 + tt*4 + (t - 4));
        float* dst = part + ((size_t)c * S + tb*256 + token) * E + ee*8;
        *(float4*)(dst)     = make_float4(acc[t*8+0], acc[t*8+1], acc[t*8+2], acc[t*8+3]);
        *(float4*)(dst + 4) = make_float4(acc[t*8+4], acc[t*8+5], acc[t*8+6], acc[t*8+7]);
    }
}

// ---------------- K1b: reduce partials, softmax, argmax, me atomics ----------
__global__ __launch_bounds__(256, 1)
void k1b_softmax(const float* __restrict__ part, float* __restrict__ gate_val,
                 int* __restrict__ idx1, int* __restrict__ counts,
                 float* __restrict__ me_sum) {
    const int tid = threadIdx.x, wv = tid >> 6, ln = tid & 63;
    const int token = blockIdx.x * 4 + wv;
    float p = 0.f;
    #pragma unroll
    for (int c = 0; c < CCH; c++) p += part[((size_t)c * S + token) * E + ln];
    // argmax (max value, lowest index on ties) — matches jnp.argmax
    float v = p; int i = ln;
    #pragma unroll
    for (int off = 1; off < 64; off <<= 1) {
        float ov = __shfl_xor(v, off, 64);
        int   oi = __shfl_xor(i, off, 64);
        if (ov > v || (ov == v && oi < i)) { v = ov; i = oi; }
    }
    float g = __expf(p - v);
    float ssum = g;
    #pragma unroll
    for (int off = 1; off < 64; off <<= 1) ssum += __shfl_xor(ssum, off, 64);
    const float gate = g / ssum;
    __shared__ float gs[4][64];
    gs[wv][ln] = gate;
    __syncthreads();
    if (tid < 64)
        atomicAdd(&me_sum[tid], gs[0][tid] + gs[1][tid] + gs[2][tid] + gs[3][tid]);
    if (ln == 0) {
        gate_val[token] = 1.0f / ssum;
        idx1[token] = i;
        atomicAdd(&counts[i], 1);
    }
}

// ---------------- K2: per-expert capacity selection + scatter ----------------
__device__ __forceinline__ int block_reduce_sum(int v, int* tmp4, int tid) {
    #pragma unroll
    for (int off = 1; off < 64; off <<= 1) v += __shfl_xor(v, off, 64);
    __syncthreads();
    if ((tid & 63) == 0) tmp4[tid >> 6] = v;
    __syncthreads();
    return tmp4[0] + tmp4[1] + tmp4[2] + tmp4[3];
}

__device__ __forceinline__ int block_scan_incl(int val, int* a, int* b, int tid, int* total) {
    __syncthreads();
    a[tid] = val;
    __syncthreads();
    int* src = a; int* dst = b;
    #pragma unroll
    for (int off = 1; off < 256; off <<= 1) {
        int v = src[tid];
        if (tid >= off) v += src[tid - off];
        dst[tid] = v;
        __syncthreads();
        int* t = src; src = dst; dst = t;
    }
    *total = src[255];
    return src[tid];
}

__global__ __launch_bounds__(256, 1)
void k2_select(const int* __restrict__ idx1, const float* __restrict__ gate_val,
               const float* __restrict__ noise, const int* __restrict__ counts,
               const float* __restrict__ me_sum, float* __restrict__ out) {
    const int e = blockIdx.x;
    const int tid = threadIdx.x;
    __shared__ int idx_s[S];
    __shared__ unsigned short l_tok[S];
    __shared__ float l_ns[S];
    __shared__ int sa[256], sb[256];
    __shared__ int tmp4[4];

    for (int i = tid; i < S; i += 256) idx_s[i] = idx1[i];
    __syncthreads();

    int cnt = 0;
    #pragma unroll
    for (int j4 = 0; j4 < 8; j4++) {
        const int4 q = *(const int4*)&idx_s[tid * 32 + j4 * 4];
        cnt += (q.x == e) + (q.y == e) + (q.z == e) + (q.w == e);
    }
    int total_n;
    int incl = block_scan_incl(cnt, sa, sb, tid, &total_n);
    int pos = incl - cnt;
    const int n = total_n;
    #pragma unroll
    for (int j4 = 0; j4 < 8; j4++) {
        const int4 q = *(const int4*)&idx_s[tid * 32 + j4 * 4];
        const int qv[4] = {q.x, q.y, q.z, q.w};
        #pragma unroll
        for (int u = 0; u < 4; u++) {
            const int s = tid * 32 + j4 * 4 + u;
            if (qv[u] == e) {
                l_tok[pos] = (unsigned short)s;
                l_ns[pos]  = noise[(size_t)s * E + e];
                pos++;
            }
        }
    }
    __syncthreads();

    if (tid == 0) out[EC_OFF + e] = (float)n;   // exp_counts (pre-capacity)

    // 128th-largest noise via binary search on positive-float bit patterns
    unsigned int V = 0u;
    if (n > CAP) {
        unsigned int lo = 0u, hi = 0x3F800000u;
        while (hi - lo > 1u) {
            const unsigned int mid = (lo + hi) >> 1;
            int c = 0;
            for (int i2 = tid; i2 < n; i2 += 256)
                c += (__float_as_uint(l_ns[i2]) >= mid);
            const int cge = block_reduce_sum(c, tmp4, tid);
            if (cge >= CAP) lo = mid; else hi = mid;
        }
        V = lo;
    }

    const int m = (n + 255) >> 8;
    const int i_begin = min(n, tid * m);
    const int i_end   = min(n, i_begin + m);
    int gt_l = 0, eq_l = 0;
    for (int i2 = i_begin; i2 < i_end; i2++) {
        const unsigned int b = __float_as_uint(l_ns[i2]);
        gt_l += (b > V); eq_l += (b == V);
    }
    int tot_gt, tot_eq;
    const int incl_gt = block_scan_incl(gt_l, sa, sb, tid, &tot_gt);
    (void)incl_gt;
    const int incl_eq = block_scan_incl(eq_l, sa, sb, tid, &tot_eq);
    const int eq_excl = incl_eq - eq_l;
    const int take_eq = CAP - tot_gt;   // ties -> lowest token index (jax top_k stable)
    const int sel_l = gt_l + max(0, min(eq_l, take_eq - eq_excl));
    int tot_sel;
    const int incl_sel = block_scan_incl(sel_l, sa, sb, tid, &tot_sel);
    int slot = incl_sel - sel_l;
    int eq_seen = eq_excl;
    for (int i2 = i_begin; i2 < i_end; i2++) {
        const unsigned int b = __float_as_uint(l_ns[i2]);
        bool sel;
        if (b > V) sel = true;
        else if (b == V) { sel = (eq_seen < take_eq); eq_seen++; }
        else sel = false;
        if (sel) {
            const int tok = l_tok[i2];
            const float g = gate_val[tok];
            const size_t off = (size_t)tok * (E * CAP) + (size_t)e * CAP + slot;
            out[CW_OFF + off] = g;
            out[DM_OFF + off] = 1.0f;
            slot++;
        }
    }

    if (e == 0 && tid < 64) {
        float la = (me_sum[tid] / (float)S) * ((float)counts[tid] / (float)S);
        #pragma unroll
        for (int off = 1; off < 64; off <<= 1) la += __shfl_xor(la, off, 64);
        if (tid == 0) out[0] = la * (float)E;
    }
}

extern "C" void kernel_launch(void* const* d_in, const int* in_sizes, int n_in,
                              void* d_out, int out_size, void* d_ws, size_t ws_size,
                              hipStream_t stream) {
    const float* x     = (const float*)d_in[0];
    const float* wg    = (const float*)d_in[1];
    const float* noise = (const float*)d_in[2];
    float* out = (float*)d_out;
    float* ws  = (float*)d_ws;

    float* gate_val = ws;                   // 8192 f32
    int*   idx1     = (int*)(ws + 8192);    // 8192 i32
    int*   counts   = (int*)(ws + 16384);   // 64 i32
    float* me_sum   = ws + 16448;           // 64 f32
    float* part     = ws + 16512;           // 32*8192*64 f32 = 67 MB (L2/L3-resident)

    hipMemsetAsync(counts, 0, 128 * sizeof(int), stream);      // counts + me_sum
    hipMemsetAsync(out, 0, (size_t)out_size * sizeof(float), stream);
    k1_partial  <<<dim3(1024), dim3(256), 0, stream>>>(x, wg, part);
    k1b_softmax <<<dim3(S/4),  dim3(256), 0, stream>>>(part, gate_val, idx1, counts, me_sum);
    k2_select   <<<dim3(E),    dim3(256), 0, stream>>>(idx1, gate_val, noise, counts, me_sum, out);
}